// Round 4
// baseline (464.031 us; speedup 1.0000x reference)
//
#include <hip/hip_runtime.h>
#include <stdint.h>

#define Hdim 1024
#define Bdim 8
#define Sdim 2048
#define Edim 8
#define Mtot 16384
#define Ntot 8192   // n' = d*8 + e

typedef short bf16x8 __attribute__((ext_vector_type(8)));
typedef unsigned short u16x8 __attribute__((ext_vector_type(8)));
typedef float f32x4 __attribute__((ext_vector_type(4)));

__device__ __forceinline__ unsigned short f2bf(float f) {
  union { float f; unsigned u; } v; v.f = f;
  unsigned r = (v.u + 0x7FFFu + ((v.u >> 16) & 1u)) >> 16;
  return (unsigned short)r;
}

__device__ __forceinline__ void gload16(const void* g, void* l) {
  __builtin_amdgcn_global_load_lds((const __attribute__((address_space(1))) void*)g,
                                   (__attribute__((address_space(3))) void*)l,
                                   16, 0, 0);
}

#define VMCNT_(N) asm volatile("s_waitcnt vmcnt(" #N ")" ::: "memory")
#define VMCNT(N) VMCNT_(N)
#define LGKM_(N) asm volatile("s_waitcnt lgkmcnt(" #N ")" ::: "memory")
#define LGKM(N) LGKM_(N)
#define SCHED0() __builtin_amdgcn_sched_barrier(0)
#define BAR() __builtin_amdgcn_s_barrier()

// ---------------- kernel 1: f32 -> bf16 convert + per-(b,h) partial sums over s ----
__global__ void k_convert_mean(const float* __restrict__ x,
                               unsigned short* __restrict__ xb,
                               float* __restrict__ part) {
  const int b = blockIdx.y;
  const int s0 = blockIdx.x * 32;
  const int t = threadIdx.x;
  const int hg = (t & 127) << 3;
  const int sp = t >> 7;
  float accv[8];
#pragma unroll
  for (int q = 0; q < 8; ++q) accv[q] = 0.f;
#pragma unroll 4
  for (int i = 0; i < 16; ++i) {
    const int s = s0 + sp + (i << 1);
    const size_t base = ((size_t)b * Sdim + s) * Hdim + hg;
    const float4 lo = *(const float4*)(x + base);
    const float4 hi = *(const float4*)(x + base + 4);
    accv[0] += lo.x; accv[1] += lo.y; accv[2] += lo.z; accv[3] += lo.w;
    accv[4] += hi.x; accv[5] += hi.y; accv[6] += hi.z; accv[7] += hi.w;
    u16x8 pk;
    pk[0] = f2bf(lo.x); pk[1] = f2bf(lo.y); pk[2] = f2bf(lo.z); pk[3] = f2bf(lo.w);
    pk[4] = f2bf(hi.x); pk[5] = f2bf(hi.y); pk[6] = f2bf(hi.z); pk[7] = f2bf(hi.w);
    *(u16x8*)(xb + base) = pk;
  }
  float* pp = part + ((size_t)b * 128 + blockIdx.x * 2 + sp) * Hdim + hg;
#pragma unroll
  for (int q = 0; q < 8; ++q) pp[q] = accv[q];
}

// ---------------- kernel 2: We [E][H][H] f32 -> wt [(d*8+e)][h] bf16 ----------------
__global__ void k_transpose_w(const float* __restrict__ We,
                              unsigned short* __restrict__ wt) {
  __shared__ float lds[64][65];
  const int e = blockIdx.z, hb = blockIdx.y, db = blockIdx.x;
  const int t = threadIdx.x;
  const float* src = We + ((size_t)e * Hdim + hb * 64) * Hdim + db * 64;
#pragma unroll 4
  for (int it = 0; it < 16; ++it) {
    int idx = it * 256 + t;
    int r = idx >> 6, c = idx & 63;
    lds[r][c] = src[(size_t)r * Hdim + c];
  }
  __syncthreads();
#pragma unroll 4
  for (int it = 0; it < 16; ++it) {
    int idx = it * 256 + t;
    int r = idx >> 6, c = idx & 63;   // r = d_local, c = h_local
    const int np = (db * 64 + r) * 8 + e;
    wt[(size_t)np * Hdim + hb * 64 + c] = f2bf(lds[c][r]);
  }
}

// ---------------- kernel 3: finish mean + h = relu(xm @ Wr1 + br1) -----------------
__global__ void k_router1(const float* __restrict__ part,
                          const float* __restrict__ Wr1,
                          const float* __restrict__ br1,
                          float* __restrict__ hbuf) {
  __shared__ float xm[Hdim];
  const int b = blockIdx.y, jc = blockIdx.x, t = threadIdx.x;
  for (int k = t; k < Hdim; k += 256) {
    float s = 0.f;
    const float* p = part + (size_t)b * 128 * Hdim + k;
#pragma unroll 8
    for (int c = 0; c < 128; ++c) s += p[(size_t)c * Hdim];
    xm[k] = s * (1.0f / 2048.0f);
  }
  __syncthreads();
  const int j = jc * 256 + t;
  float acc = br1[j];
#pragma unroll 8
  for (int k = 0; k < Hdim; ++k) acc = fmaf(xm[k], Wr1[(size_t)k * Hdim + j], acc);
  hbuf[b * Hdim + j] = fmaxf(acc, 0.f);
}

// ---------------- kernel 4: logits + softmax -> routing [B][E] ---------------------
__global__ void k_router2(const float* __restrict__ hbuf,
                          const float* __restrict__ Wr2,
                          const float* __restrict__ br2,
                          float* __restrict__ routing) {
  const int t = threadIdx.x;
  const int e = t & 7;
  const int b = t >> 3;
  float acc = br2[e];
  const float* hb = hbuf + b * Hdim;
#pragma unroll 8
  for (int k = 0; k < Hdim; ++k) acc = fmaf(hb[k], Wr2[k * Edim + e], acc);
  float m = acc;
  for (int d = 1; d < 8; d <<= 1) m = fmaxf(m, __shfl_xor(m, d, 64));
  float p = __expf(acc - m);
  float s = p;
  for (int d = 1; d < 8; d <<= 1) s += __shfl_xor(s, d, 64);
  routing[t] = p / s;
}

// ---------------- kernel 5: 8-phase pipelined 256x256 GEMM 16384 x 8192 x 1024 -----
// 8 waves (2M x 4N), per-wave 128x64. 2 K-tiles (BK=64) per iteration, 8 phases.
// ds_reads issued 1-2 phases ahead of consuming MFMA; counted lgkm at p0/p2/p4/p6;
// vmcnt(4) at p2end/p6end only. LDS: A buf0/1 @ 0/32768, B buf0/1 @ 65536/98304.
__global__ __launch_bounds__(512, 2)
void k_moe_gemm(const unsigned short* __restrict__ xb,
                const unsigned short* __restrict__ wt,
                const float* __restrict__ be,
                const float* __restrict__ routing,
                float* __restrict__ out) {
  extern __shared__ char smem[];
  const int t = threadIdx.x;
  const int wave = t >> 6, lane = t & 63;
  const int la15 = lane & 15;
  const int wr = wave >> 2;    // 0..1
  const int wcn = wave & 3;    // 0..3

  // bijective XCD swizzle (2048 % 8 == 0)
  const int bid = blockIdx.x;
  const int wg = (bid & 7) * 256 + (bid >> 3);
  const int m0 = (wg >> 5) * 256;
  const int n0 = (wg & 31) * 256;

  // staging: thread covers row base + (lane>>3), phys chunk lane&7,
  // global logical chunk = (lane&7) ^ (lane>>3)
  const int cx = (((lane & 7) ^ (lane >> 3)) << 3);
  const unsigned short* aStage = xb + (size_t)(m0 + wave * 8 + (lane >> 3)) * Hdim + cx;
  const int bRowLoc = ((wave & 3) << 3) + ((wave >> 2) << 6) + (lane >> 3);
  const unsigned short* bStage = wt + (size_t)(n0 + bRowLoc) * Hdim + cx;
  const int aLdsW = wave * 1024;
  const int bLdsW = ((wave & 3) << 10) + ((wave >> 2) << 13);

  // ds_read bases (phys chunk = logical ^ (row&7), row&7 == lane&7)
  const int swz0 = (((lane >> 4) ^ (lane & 7)) << 4);
  const int swz1 = ((((lane >> 4) + 4) ^ (lane & 7)) << 4);
  const int aRd = (wr * 128 + la15) * 128;
  const int bRd = (wcn * 64 + la15) * 128;

  f32x4 acc[8][4];
#pragma unroll
  for (int i = 0; i < 8; ++i)
#pragma unroll
    for (int j = 0; j < 4; ++j) acc[i][j] = (f32x4){0.f, 0.f, 0.f, 0.f};

  bf16x8 a0[4][2], a1[4][2], b0[2][2], b1[2][2];

#define STG_A(half, buf, k0) do { \
    gload16(aStage + (half) * 64 * 1024 + (k0),          smem + (buf) * 32768 + aLdsW + (half) * 8192); \
    gload16(aStage + (128 + (half) * 64) * 1024 + (k0),  smem + (buf) * 32768 + aLdsW + 16384 + (half) * 8192); \
  } while (0)
#define STG_B(sub, buf, k0) do { \
    gload16(bStage + (sub) * 32 * 1024 + (k0),           smem + 65536 + (buf) * 32768 + bLdsW + (sub) * 4096); \
    gload16(bStage + (128 + (sub) * 32) * 1024 + (k0),   smem + 65536 + (buf) * 32768 + bLdsW + 16384 + (sub) * 4096); \
  } while (0)
#define LD_A(dst, buf, qi) do { \
    _Pragma("unroll") for (int ii = 0; ii < 4; ++ii) { \
      dst[ii][0] = *(const bf16x8*)(smem + (buf) * 32768 + aRd + (qi) * 8192 + ii * 2048 + swz0); \
      dst[ii][1] = *(const bf16x8*)(smem + (buf) * 32768 + aRd + (qi) * 8192 + ii * 2048 + swz1); } \
  } while (0)
#define LD_A_LO(dst, buf, qi) do { \
    _Pragma("unroll") for (int ii = 0; ii < 2; ++ii) { \
      dst[ii][0] = *(const bf16x8*)(smem + (buf) * 32768 + aRd + (qi) * 8192 + ii * 2048 + swz0); \
      dst[ii][1] = *(const bf16x8*)(smem + (buf) * 32768 + aRd + (qi) * 8192 + ii * 2048 + swz1); } \
  } while (0)
#define LD_A_HI(dst, buf, qi) do { \
    _Pragma("unroll") for (int ii = 2; ii < 4; ++ii) { \
      dst[ii][0] = *(const bf16x8*)(smem + (buf) * 32768 + aRd + (qi) * 8192 + ii * 2048 + swz0); \
      dst[ii][1] = *(const bf16x8*)(smem + (buf) * 32768 + aRd + (qi) * 8192 + ii * 2048 + swz1); } \
  } while (0)
#define LD_B(dst, buf, qj) do { \
    _Pragma("unroll") for (int jj = 0; jj < 2; ++jj) { \
      dst[jj][0] = *(const bf16x8*)(smem + 65536 + (buf) * 32768 + bRd + (qj) * 4096 + jj * 2048 + swz0); \
      dst[jj][1] = *(const bf16x8*)(smem + 65536 + (buf) * 32768 + bRd + (qj) * 4096 + jj * 2048 + swz1); } \
  } while (0)
#define MF_Q(af_, bf_, qi, jh) do { \
    __builtin_amdgcn_s_setprio(1); \
    _Pragma("unroll") for (int ii = 0; ii < 4; ++ii) \
      _Pragma("unroll") for (int jj = 0; jj < 2; ++jj) { \
        acc[(qi)*4+ii][(jh)*2+jj] = __builtin_amdgcn_mfma_f32_16x16x32_bf16(af_[ii][0], bf_[jj][0], acc[(qi)*4+ii][(jh)*2+jj], 0, 0, 0); \
        acc[(qi)*4+ii][(jh)*2+jj] = __builtin_amdgcn_mfma_f32_16x16x32_bf16(af_[ii][1], bf_[jj][1], acc[(qi)*4+ii][(jh)*2+jj], 0, 0, 0); } \
    __builtin_amdgcn_s_setprio(0); \
  } while (0)

  // ---- prologue: stage tile0 (buf0) + tile1 (buf1); VMCNT(6) covers units 1-5 ----
  STG_A(0, 0, 0);    // #1 buf0.A.ha t0
  STG_B(1, 0, 0);    // #2 buf0.B.hb t0
  STG_B(0, 0, 0);    // #3 buf0.B.ha t0
  STG_A(1, 0, 0);    // #4 buf0.A.hb t0
  STG_A(0, 1, 64);   // #5 buf1.A.ha t1
  SCHED0();
  STG_B(1, 1, 64);   // #6 buf1.B.hb t1
  STG_B(0, 1, 64);   // #7 buf1.B.ha t1
  STG_A(1, 1, 64);   // #8 buf1.A.hb t1
  VMCNT(6);
  BAR();
  LD_A(a0, 0, 0);    // a0 <- buf0.A.ha (t0) [8]
  SCHED0();
  LD_B(b1, 0, 1);    // bB <- buf0.B.hb (t0) [4]

#pragma unroll 1
  for (int j = 0; j < 8; ++j) {
    const int k2 = (j * 128 + 128) & 1023;   // tile 2j+2 (buf0 restage)
    const int k3 = (j * 128 + 192) & 1023;   // tile 2j+3 (buf1 restage)
    // p0: MFMA a0 x bA (T0 q00). reads: bA [4], a1lo [4]. stage buf0.A.ha(k2).
    LD_B(b0, 0, 0);
    SCHED0();
    LD_A_LO(a1, 0, 1);
    STG_A(0, 0, k2);
    BAR(); LGKM(4); SCHED0();
    MF_Q(a0, b0, 0, 0);
    BAR();
    // p1: MFMA a0 x bB (T0 q01). reads: a1hi [4]. stage buf0.B.ha(k2).
    LD_A_HI(a1, 0, 1);
    STG_B(0, 0, k2);
    BAR(); SCHED0();
    MF_Q(a0, b1, 0, 1);
    BAR();
    // p2: MFMA a1 x bB (T0 q11). reads: a0n <- buf1.A.ha [8]. stage buf0.B.hb(k2). VMCNT.
    LD_A(a0, 1, 0);
    STG_B(1, 0, k2);
    VMCNT(4);
    BAR(); LGKM(8); SCHED0();
    MF_Q(a1, b1, 1, 1);
    BAR();
    // p3: MFMA a1 x bA (T0 q10). reads: bD <- buf1.B.hb [4]. stage buf0.A.hb(k2).
    LD_B(b1, 1, 1);
    STG_A(1, 0, k2);
    BAR(); SCHED0();
    MF_Q(a1, b0, 1, 0);
    BAR();
    // p4: MFMA a0 x bC (T1 q00). reads: bC [4], a1lo' [4]. stage buf1.A.ha(k3).
    LD_B(b0, 1, 0);
    SCHED0();
    LD_A_LO(a1, 1, 1);
    STG_A(0, 1, k3);
    BAR(); LGKM(4); SCHED0();
    MF_Q(a0, b0, 0, 0);
    BAR();
    // p5: MFMA a0 x bD (T1 q01). reads: a1hi' [4]. stage buf1.B.ha(k3).
    LD_A_HI(a1, 1, 1);
    STG_B(0, 1, k3);
    BAR(); SCHED0();
    MF_Q(a0, b1, 0, 1);
    BAR();
    // p6: MFMA a1 x bD (T1 q11). reads: a0'' <- buf0.A.ha(t2j+2) [8]. stage buf1.B.hb(k3). VMCNT.
    LD_A(a0, 0, 0);
    STG_B(1, 1, k3);
    VMCNT(4);
    BAR(); LGKM(8); SCHED0();
    MF_Q(a1, b1, 1, 1);
    BAR();
    // p7: MFMA a1 x bC (T1 q10). reads: bB' <- buf0.B.hb(t2j+2) [4]. stage buf1.A.hb(k3).
    LD_B(b1, 0, 1);
    STG_A(1, 1, k3);
    BAR(); SCHED0();
    MF_Q(a1, b0, 1, 0);
    BAR();
  }

  VMCNT(0);   // drain tail stages before LDS reuse
  BAR();

  // ---------------- epilogue: bias + relu + routing weight + e-reduce ----------------
  float* outb = (float*)smem;                 // [256][33] padded
  const int bidx = m0 >> 11;
  const float rw = routing[bidx * Edim + (lane & 7)];
  const int dblk = (lane >> 3) & 1;
  const bool writer = ((lane & 7) == 0);
#pragma unroll
  for (int j = 0; j < 4; ++j) {
    const int col0 = wcn * 64 + j * 16;
    const float bias = be[(lane & 7) * Hdim + (n0 >> 3) + (col0 >> 3) + dblk];
#pragma unroll
    for (int i = 0; i < 8; ++i) {
#pragma unroll
      for (int r = 0; r < 4; ++r) {
        float v = fmaxf(acc[i][j][r] + bias, 0.f) * rw;
        v += __shfl_xor(v, 1, 64);
        v += __shfl_xor(v, 2, 64);
        v += __shfl_xor(v, 4, 64);
        if (writer) {
          const int row = wr * 128 + i * 16 + ((lane >> 4) << 2) + r;
          outb[row * 33 + (col0 >> 3) + dblk] = v;
        }
      }
    }
  }
  BAR();
  const size_t obase = (size_t)m0 * Hdim + (n0 >> 3);
#pragma unroll
  for (int it = 0; it < 4; ++it) {
    const int r = it * 64 + (t >> 3);
    const int c = (t & 7) * 4;
    float4 vv;
    vv.x = outb[r * 33 + c];
    vv.y = outb[r * 33 + c + 1];
    vv.z = outb[r * 33 + c + 2];
    vv.w = outb[r * 33 + c + 3];
    *(float4*)(out + obase + (size_t)r * Hdim + c) = vv;
  }
#undef STG_A
#undef STG_B
#undef LD_A
#undef LD_A_LO
#undef LD_A_HI
#undef LD_B
#undef MF_Q
}

extern "C" void kernel_launch(void* const* d_in, const int* in_sizes, int n_in,
                              void* d_out, int out_size, void* d_ws, size_t ws_size,
                              hipStream_t stream) {
  const float* x   = (const float*)d_in[0];
  const float* We  = (const float*)d_in[1];
  const float* be  = (const float*)d_in[2];
  const float* Wr1 = (const float*)d_in[3];
  const float* br1 = (const float*)d_in[4];
  const float* Wr2 = (const float*)d_in[5];
  const float* br2 = (const float*)d_in[6];
  float* out = (float*)d_out;

  char* ws = (char*)d_ws;
  unsigned short* xb = (unsigned short*)ws;                  // 33,554,432 B
  unsigned short* wt = (unsigned short*)(ws + 33554432);     // 16,777,216 B
  float* part    = (float*)(ws + 50331648);                  //  4,194,304 B
  float* hbuf    = (float*)(ws + 54525952);                  //     32,768 B
  float* routing = (float*)(ws + 54558720);                  //        256 B

  hipFuncSetAttribute((const void*)k_moe_gemm,
                      hipFuncAttributeMaxDynamicSharedMemorySize, 131072);

  k_convert_mean<<<dim3(Sdim / 32, Bdim), 256, 0, stream>>>(x, xb, part);
  k_transpose_w<<<dim3(Hdim / 64, Hdim / 64, Edim), 256, 0, stream>>>(We, wt);
  k_router1<<<dim3(Hdim / 256, Bdim), 256, 0, stream>>>(part, Wr1, br1, hbuf);
  k_router2<<<1, 64, 0, stream>>>(hbuf, Wr2, br2, routing);
  k_moe_gemm<<<dim3(2048), 512, 131072, stream>>>(xb, wt, be, routing, out);
}

// Round 5
// 421.523 us; speedup vs baseline: 1.1008x; 1.1008x over previous
//
#include <hip/hip_runtime.h>
#include <stdint.h>

#define Hdim 1024
#define Bdim 8
#define Sdim 2048
#define Edim 8
#define Mtot 16384
#define Ntot 8192   // n' = d*8 + e

typedef short bf16x8 __attribute__((ext_vector_type(8)));
typedef unsigned short u16x8 __attribute__((ext_vector_type(8)));
typedef float f32x4 __attribute__((ext_vector_type(4)));

__device__ __forceinline__ unsigned short f2bf(float f) {
  union { float f; unsigned u; } v; v.f = f;
  unsigned r = (v.u + 0x7FFFu + ((v.u >> 16) & 1u)) >> 16;
  return (unsigned short)r;
}

__device__ __forceinline__ void gload16(const void* g, void* l) {
  __builtin_amdgcn_global_load_lds((const __attribute__((address_space(1))) void*)g,
                                   (__attribute__((address_space(3))) void*)l,
                                   16, 0, 0);
}

#define VMCNT_(N) asm volatile("s_waitcnt vmcnt(" #N ")" ::: "memory")
#define VMCNT(N) VMCNT_(N)
#define BAR() __builtin_amdgcn_s_barrier()

// ---------------- kernel 1: f32 -> bf16 convert + per-(b,h) partial sums over s ----
__global__ void k_convert_mean(const float* __restrict__ x,
                               unsigned short* __restrict__ xb,
                               float* __restrict__ part) {
  const int b = blockIdx.y;
  const int s0 = blockIdx.x * 32;
  const int t = threadIdx.x;
  const int hg = (t & 127) << 3;
  const int sp = t >> 7;
  float accv[8];
#pragma unroll
  for (int q = 0; q < 8; ++q) accv[q] = 0.f;
#pragma unroll 4
  for (int i = 0; i < 16; ++i) {
    const int s = s0 + sp + (i << 1);
    const size_t base = ((size_t)b * Sdim + s) * Hdim + hg;
    const float4 lo = *(const float4*)(x + base);
    const float4 hi = *(const float4*)(x + base + 4);
    accv[0] += lo.x; accv[1] += lo.y; accv[2] += lo.z; accv[3] += lo.w;
    accv[4] += hi.x; accv[5] += hi.y; accv[6] += hi.z; accv[7] += hi.w;
    u16x8 pk;
    pk[0] = f2bf(lo.x); pk[1] = f2bf(lo.y); pk[2] = f2bf(lo.z); pk[3] = f2bf(lo.w);
    pk[4] = f2bf(hi.x); pk[5] = f2bf(hi.y); pk[6] = f2bf(hi.z); pk[7] = f2bf(hi.w);
    *(u16x8*)(xb + base) = pk;
  }
  float* pp = part + ((size_t)b * 128 + blockIdx.x * 2 + sp) * Hdim + hg;
#pragma unroll
  for (int q = 0; q < 8; ++q) pp[q] = accv[q];
}

// ---------------- kernel 2: We [E][H][H] f32 -> wt [(d*8+e)][h] bf16 ----------------
__global__ void k_transpose_w(const float* __restrict__ We,
                              unsigned short* __restrict__ wt) {
  __shared__ float lds[64][65];
  const int e = blockIdx.z, hb = blockIdx.y, db = blockIdx.x;
  const int t = threadIdx.x;
  const float* src = We + ((size_t)e * Hdim + hb * 64) * Hdim + db * 64;
#pragma unroll 4
  for (int it = 0; it < 16; ++it) {
    int idx = it * 256 + t;
    int r = idx >> 6, c = idx & 63;
    lds[r][c] = src[(size_t)r * Hdim + c];
  }
  __syncthreads();
#pragma unroll 4
  for (int it = 0; it < 16; ++it) {
    int idx = it * 256 + t;
    int r = idx >> 6, c = idx & 63;   // r = d_local, c = h_local
    const int np = (db * 64 + r) * 8 + e;
    wt[(size_t)np * Hdim + hb * 64 + c] = f2bf(lds[c][r]);
  }
}

// ---------------- kernel 3a: finish mean -> xm [B][H] ------------------------------
// grid (16, 8), 256 threads
__global__ void k_mean(const float* __restrict__ part, float* __restrict__ xm) {
  __shared__ float red[4][64];
  const int b = blockIdx.y, hc = blockIdx.x, t = threadIdx.x;
  const int h = hc * 64 + (t & 63), q = t >> 6;
  float s = 0.f;
  const float* p = part + ((size_t)b * 128 + q * 32) * Hdim + h;
#pragma unroll 8
  for (int c = 0; c < 32; ++c) s += p[(size_t)c * Hdim];
  red[q][t & 63] = s;
  __syncthreads();
  if (t < 64) {
    float v = (red[0][t] + red[1][t]) + (red[2][t] + red[3][t]);
    xm[b * Hdim + hc * 64 + t] = v * (1.0f / 2048.0f);
  }
}

// ---------------- kernel 3b: h = relu(xm @ Wr1 + br1) ------------------------------
// grid (8, 8), 256 threads: j = jc*128 + (t&127), k-half = t>>7
__global__ void k_r1(const float* __restrict__ xm,
                     const float* __restrict__ Wr1,
                     const float* __restrict__ br1,
                     float* __restrict__ hbuf) {
  __shared__ float xs[Hdim];
  __shared__ float hred[2][128];
  const int b = blockIdx.y, jc = blockIdx.x, t = threadIdx.x;
  for (int k = t; k < Hdim; k += 256) xs[k] = xm[b * Hdim + k];
  __syncthreads();
  const int j = jc * 128 + (t & 127);
  const int kh = (t >> 7) * 512;
  float acc = 0.f;
#pragma unroll 8
  for (int k = 0; k < 512; ++k)
    acc = fmaf(xs[kh + k], Wr1[(size_t)(kh + k) * Hdim + j], acc);
  hred[t >> 7][t & 127] = acc;
  __syncthreads();
  if (t < 128)
    hbuf[b * Hdim + jc * 128 + t] =
        fmaxf(hred[0][t] + hred[1][t] + br1[jc * 128 + t], 0.f);
}

// ---------------- kernel 4: logits + softmax -> routing [B][E] ---------------------
__global__ void k_router2(const float* __restrict__ hbuf,
                          const float* __restrict__ Wr2,
                          const float* __restrict__ br2,
                          float* __restrict__ routing) {
  const int t = threadIdx.x;
  const int e = t & 7;
  const int b = t >> 3;
  float acc = br2[e];
  const float* hb = hbuf + b * Hdim;
#pragma unroll 8
  for (int k = 0; k < Hdim; ++k) acc = fmaf(hb[k], Wr2[k * Edim + e], acc);
  float m = acc;
  for (int d = 1; d < 8; d <<= 1) m = fmaxf(m, __shfl_xor(m, d, 64));
  float p = __expf(acc - m);
  float s = p;
  for (int d = 1; d < 8; d <<= 1) s += __shfl_xor(s, d, 64);
  routing[t] = p / s;
}

// ---------------- kernel 5: 8-phase pipelined 256x256 GEMM 16384 x 8192 x 1024 -----
// 8 waves (2M x 4N), per-wave 128x64. 2 K-tiles (BK=64) per iteration, 8 phases.
// L2-blocked mapping: XCD x owns m-band [x*8, x*8+8) (A band 4MB, L2-resident);
// each round of 32 blocks covers band x 4 n-tiles (B 2MB/round, 8x in-round reuse).
// VMCNT(4) at ends of p1/p5 only (FIFO-traced: every unit drains >=1 barrier
// before its first cross-wave read). Compiler handles lgkm.
__global__ __launch_bounds__(512, 2)
void k_moe_gemm(const unsigned short* __restrict__ xb,
                const unsigned short* __restrict__ wt,
                const float* __restrict__ be,
                const float* __restrict__ routing,
                float* __restrict__ out) {
  extern __shared__ char smem[];
  const int t = threadIdx.x;
  const int wave = t >> 6, lane = t & 63;
  const int la15 = lane & 15;
  const int wr = wave >> 2;    // 0..1
  const int wcn = wave & 3;    // 0..3

  // L2-blocked bijective mapping
  const int bid = blockIdx.x;
  const int xcd = bid & 7;
  const int idx = bid >> 3;          // 0..255
  const int rnd = idx >> 5;          // 0..7
  const int slot = idx & 31;         // 0..31
  const int m0 = (xcd * 8 + (slot & 7)) * 256;
  const int n0 = (rnd * 4 + (slot >> 3)) * 256;

  // staging: thread covers row base + (lane>>3), phys chunk lane&7,
  // global logical chunk = (lane&7) ^ (lane>>3)
  const int cx = (((lane & 7) ^ (lane >> 3)) << 3);
  const unsigned short* aStage = xb + (size_t)(m0 + wave * 8 + (lane >> 3)) * Hdim + cx;
  const int bRowLoc = ((wave & 3) << 3) + ((wave >> 2) << 6) + (lane >> 3);
  const unsigned short* bStage = wt + (size_t)(n0 + bRowLoc) * Hdim + cx;
  const int aLdsW = wave * 1024;
  const int bLdsW = ((wave & 3) << 10) + ((wave >> 2) << 13);

  // ds_read bases (phys chunk = logical ^ (row&7), row&7 == lane&7)
  const int swz0 = (((lane >> 4) ^ (lane & 7)) << 4);
  const int swz1 = ((((lane >> 4) + 4) ^ (lane & 7)) << 4);
  const int aRd = (wr * 128 + la15) * 128;
  const int bRd = (wcn * 64 + la15) * 128;

  f32x4 acc[8][4];
#pragma unroll
  for (int i = 0; i < 8; ++i)
#pragma unroll
    for (int j = 0; j < 4; ++j) acc[i][j] = (f32x4){0.f, 0.f, 0.f, 0.f};

  bf16x8 a0[4][2], a1[4][2], b0[2][2], b1[2][2];

#define STG_A(half, buf, k0) do { \
    gload16(aStage + (half) * 64 * 1024 + (k0),          smem + (buf) * 32768 + aLdsW + (half) * 8192); \
    gload16(aStage + (128 + (half) * 64) * 1024 + (k0),  smem + (buf) * 32768 + aLdsW + 16384 + (half) * 8192); \
  } while (0)
#define STG_B(sub, buf, k0) do { \
    gload16(bStage + (sub) * 32 * 1024 + (k0),           smem + 65536 + (buf) * 32768 + bLdsW + (sub) * 4096); \
    gload16(bStage + (128 + (sub) * 32) * 1024 + (k0),   smem + 65536 + (buf) * 32768 + bLdsW + 16384 + (sub) * 4096); \
  } while (0)
#define LD_A(dst, buf, qi) do { \
    _Pragma("unroll") for (int ii = 0; ii < 4; ++ii) { \
      dst[ii][0] = *(const bf16x8*)(smem + (buf) * 32768 + aRd + (qi) * 8192 + ii * 2048 + swz0); \
      dst[ii][1] = *(const bf16x8*)(smem + (buf) * 32768 + aRd + (qi) * 8192 + ii * 2048 + swz1); } \
  } while (0)
#define LD_A_LO(dst, buf, qi) do { \
    _Pragma("unroll") for (int ii = 0; ii < 2; ++ii) { \
      dst[ii][0] = *(const bf16x8*)(smem + (buf) * 32768 + aRd + (qi) * 8192 + ii * 2048 + swz0); \
      dst[ii][1] = *(const bf16x8*)(smem + (buf) * 32768 + aRd + (qi) * 8192 + ii * 2048 + swz1); } \
  } while (0)
#define LD_A_HI(dst, buf, qi) do { \
    _Pragma("unroll") for (int ii = 2; ii < 4; ++ii) { \
      dst[ii][0] = *(const bf16x8*)(smem + (buf) * 32768 + aRd + (qi) * 8192 + ii * 2048 + swz0); \
      dst[ii][1] = *(const bf16x8*)(smem + (buf) * 32768 + aRd + (qi) * 8192 + ii * 2048 + swz1); } \
  } while (0)
#define LD_B(dst, buf, qj) do { \
    _Pragma("unroll") for (int jj = 0; jj < 2; ++jj) { \
      dst[jj][0] = *(const bf16x8*)(smem + 65536 + (buf) * 32768 + bRd + (qj) * 4096 + jj * 2048 + swz0); \
      dst[jj][1] = *(const bf16x8*)(smem + 65536 + (buf) * 32768 + bRd + (qj) * 4096 + jj * 2048 + swz1); } \
  } while (0)
#define MF_Q(af_, bf_, qi, jh) do { \
    __builtin_amdgcn_s_setprio(1); \
    _Pragma("unroll") for (int ii = 0; ii < 4; ++ii) \
      _Pragma("unroll") for (int jj = 0; jj < 2; ++jj) { \
        acc[(qi)*4+ii][(jh)*2+jj] = __builtin_amdgcn_mfma_f32_16x16x32_bf16(af_[ii][0], bf_[jj][0], acc[(qi)*4+ii][(jh)*2+jj], 0, 0, 0); \
        acc[(qi)*4+ii][(jh)*2+jj] = __builtin_amdgcn_mfma_f32_16x16x32_bf16(af_[ii][1], bf_[jj][1], acc[(qi)*4+ii][(jh)*2+jj], 0, 0, 0); } \
    __builtin_amdgcn_s_setprio(0); \
  } while (0)

  // ---- prologue: stage t0 {Aha,Bha,Bhb,Ahb}, t1 {Aha,Bha,Bhb,Ahb}; drain t0 + t1.{Aha,Bha}
  STG_A(0, 0, 0);
  STG_B(0, 0, 0);
  STG_B(1, 0, 0);
  STG_A(1, 0, 0);
  STG_A(0, 1, 64);
  STG_B(0, 1, 64);
  STG_B(1, 1, 64);
  STG_A(1, 1, 64);
  VMCNT(4);
  BAR();
  LD_A(a0, 0, 0);    // a0 <- buf0.A.ha (t0)
  LD_B(b1, 0, 1);    // b1 <- buf0.B.hb (t0)

#pragma unroll 1
  for (int j = 0; j < 8; ++j) {
    const int k2 = (j * 128 + 128) & 1023;   // tile 2j+2 (buf0 restage)
    const int k3 = (j * 128 + 192) & 1023;   // tile 2j+3 (buf1 restage)
    // p0: MFMA a0 x b0 (T0 q00). reads b0<-buf0.Bha, a1lo<-buf0.Ahb. stage buf0.Aha(k2).
    LD_B(b0, 0, 0);
    LD_A_LO(a1, 0, 1);
    STG_A(0, 0, k2);
    BAR();
    MF_Q(a0, b0, 0, 0);
    BAR();
    // p1: MFMA a0 x b1 (T0 q01). reads a1hi. stage buf0.Bha(k2). VMCNT.
    LD_A_HI(a1, 0, 1);
    STG_B(0, 0, k2);
    VMCNT(4);
    BAR();
    MF_Q(a0, b1, 0, 1);
    BAR();
    // p2: MFMA a1 x b1 (T0 q11). reads a0<-buf1.Aha(t2j+1). stage buf0.Bhb(k2).
    LD_A(a0, 1, 0);
    STG_B(1, 0, k2);
    BAR();
    MF_Q(a1, b1, 1, 1);
    BAR();
    // p3: MFMA a1 x b0 (T0 q10). reads b1<-buf1.Bhb(t2j+1). stage buf0.Ahb(k2).
    LD_B(b1, 1, 1);
    STG_A(1, 0, k2);
    BAR();
    MF_Q(a1, b0, 1, 0);
    BAR();
    // p4: MFMA a0 x b0 (T1 q00). reads b0<-buf1.Bha, a1lo<-buf1.Ahb. stage buf1.Aha(k3).
    LD_B(b0, 1, 0);
    LD_A_LO(a1, 1, 1);
    STG_A(0, 1, k3);
    BAR();
    MF_Q(a0, b0, 0, 0);
    BAR();
    // p5: MFMA a0 x b1 (T1 q01). reads a1hi. stage buf1.Bha(k3). VMCNT.
    LD_A_HI(a1, 1, 1);
    STG_B(0, 1, k3);
    VMCNT(4);
    BAR();
    MF_Q(a0, b1, 0, 1);
    BAR();
    // p6: MFMA a1 x b1 (T1 q11). reads a0<-buf0.Aha(t2j+2). stage buf1.Bhb(k3).
    LD_A(a0, 0, 0);
    STG_B(1, 1, k3);
    BAR();
    MF_Q(a1, b1, 1, 1);
    BAR();
    // p7: MFMA a1 x b0 (T1 q10). reads b1<-buf0.Bhb(t2j+2). stage buf1.Ahb(k3).
    LD_B(b1, 0, 1);
    STG_A(1, 1, k3);
    BAR();
    MF_Q(a1, b0, 1, 0);
    BAR();
  }

  VMCNT(0);   // drain tail stages before LDS reuse
  BAR();

  // ---------------- epilogue: bias + relu + routing weight + e-reduce ----------------
  float* outb = (float*)smem;                 // [256][33] padded
  const int bidx = m0 >> 11;
  const float rw = routing[bidx * Edim + (lane & 7)];
  const int dblk = (lane >> 3) & 1;
  const bool writer = ((lane & 7) == 0);
#pragma unroll
  for (int j = 0; j < 4; ++j) {
    const int col0 = wcn * 64 + j * 16;
    const float bias = be[(lane & 7) * Hdim + (n0 >> 3) + (col0 >> 3) + dblk];
#pragma unroll
    for (int i = 0; i < 8; ++i) {
#pragma unroll
      for (int r = 0; r < 4; ++r) {
        float v = fmaxf(acc[i][j][r] + bias, 0.f) * rw;
        v += __shfl_xor(v, 1, 64);
        v += __shfl_xor(v, 2, 64);
        v += __shfl_xor(v, 4, 64);
        if (writer) {
          const int row = wr * 128 + i * 16 + ((lane >> 4) << 2) + r;
          outb[row * 33 + (col0 >> 3) + dblk] = v;
        }
      }
    }
  }
  BAR();
  const size_t obase = (size_t)m0 * Hdim + (n0 >> 3);
#pragma unroll
  for (int it = 0; it < 4; ++it) {
    const int r = it * 64 + (t >> 3);
    const int c = (t & 7) * 4;
    float4 vv;
    vv.x = outb[r * 33 + c];
    vv.y = outb[r * 33 + c + 1];
    vv.z = outb[r * 33 + c + 2];
    vv.w = outb[r * 33 + c + 3];
    *(float4*)(out + obase + (size_t)r * Hdim + c) = vv;
  }
#undef STG_A
#undef STG_B
#undef LD_A
#undef LD_A_LO
#undef LD_A_HI
#undef LD_B
#undef MF_Q
}

extern "C" void kernel_launch(void* const* d_in, const int* in_sizes, int n_in,
                              void* d_out, int out_size, void* d_ws, size_t ws_size,
                              hipStream_t stream) {
  const float* x   = (const float*)d_in[0];
  const float* We  = (const float*)d_in[1];
  const float* be  = (const float*)d_in[2];
  const float* Wr1 = (const float*)d_in[3];
  const float* br1 = (const float*)d_in[4];
  const float* Wr2 = (const float*)d_in[5];
  const float* br2 = (const float*)d_in[6];
  float* out = (float*)d_out;

  char* ws = (char*)d_ws;
  unsigned short* xb = (unsigned short*)ws;                  // 33,554,432 B
  unsigned short* wt = (unsigned short*)(ws + 33554432);     // 16,777,216 B
  float* part    = (float*)(ws + 50331648);                  //  4,194,304 B
  float* xm      = (float*)(ws + 54525952);                  //     32,768 B
  float* hbuf    = (float*)(ws + 54558720);                  //     32,768 B
  float* routing = (float*)(ws + 54591488);                  //        256 B

  hipFuncSetAttribute((const void*)k_moe_gemm,
                      hipFuncAttributeMaxDynamicSharedMemorySize, 131072);

  k_convert_mean<<<dim3(Sdim / 32, Bdim), 256, 0, stream>>>(x, xb, part);
  k_transpose_w<<<dim3(Hdim / 64, Hdim / 64, Edim), 256, 0, stream>>>(We, wt);
  k_mean<<<dim3(16, Bdim), 256, 0, stream>>>(part, xm);
  k_r1<<<dim3(8, Bdim), 256, 0, stream>>>(xm, Wr1, br1, hbuf);
  k_router2<<<1, 64, 0, stream>>>(hbuf, Wr2, br2, routing);
  k_moe_gemm<<<dim3(2048), 512, 131072, stream>>>(xb, wt, be, routing, out);
}